// Round 7
// baseline (805.106 us; speedup 1.0000x reference)
//
#include <hip/hip_runtime.h>
#include <math.h>
#include <float.h>

#define N_ROWS 32768
#define EDIM 256
#define NE 8192
#define NTILES 64            // 8192 / 128 n-tiles -> partials per row
#define DELTA 4e-3f          // rescue margin: ~5.9 sigma of dropped z.lo_e term
#define RB 8                 // rows per phase-B block

typedef unsigned int uint32;
typedef unsigned long long uint64;
typedef __attribute__((ext_vector_type(8))) short bf16x8;   // 8 bf16 = 4 VGPRs
typedef __attribute__((ext_vector_type(4))) float f32x4;

// ---- workspace layout (bytes) ----
#define OFF_ZCAT    ((size_t)0)           // 32768 x 512 bf16 [hi|lo], quarter-swizzled = 33554432
#define OFF_ECAT    ((size_t)33554432)    //  8192 x 256 bf16 hi-only, quarter-swizzled = 4194304
#define OFF_ET      ((size_t)37748736)    //  256 x 8192 f32 (E^T) = 8388608
#define OFF_EN      ((size_t)46268416)    //  8192 f
#define OFF_PV      ((size_t)46301184)    // 64 x 32768 f
#define OFF_PI      ((size_t)54689792)    // 64 x 32768 i
#define OFF_PV2     ((size_t)63078400)    // 64 x 32768 f
#define OFF_IDX     ((size_t)71467008)    // 32768 i
#define OFF_BINS    ((size_t)71598080)    //  8192 f
#define OFF_PACKED  ((size_t)71630848)    // 32768 u64 = 262144
#define OFF_FLAGCNT ((size_t)71892992)    // int (padded)
#define OFF_LOSS    ((size_t)71893248)    // double (padded)
#define OFF_FLAGGED ((size_t)71893504)    // 32768 i

__device__ __forceinline__ unsigned short f32_to_bf16_rne(float f) {
    uint32 u = __float_as_uint(f);
    uint32 r = u + 0x7fffu + ((u >> 16) & 1u);
    return (unsigned short)(r >> 16);
}

__device__ __forceinline__ void gload_lds16(const void* g, void* l) {
    __builtin_amdgcn_global_load_lds(
        (const __attribute__((address_space(1))) uint32*)g,
        (__attribute__((address_space(3))) uint32*)l, 16, 0, 0);
}

// numpy pairwise-sum emulation of sum(a*a) for n=256 (validated round 3)
__device__ __forceinline__ float np_pairwise_sumsq(const float* a) {
#pragma clang fp contract(off)
    float h0, h1;
    #pragma unroll 1
    for (int hb = 0; hb < 2; ++hb) {
        const float* p = a + hb * 128;
        float r0=p[0]*p[0], r1=p[1]*p[1], r2=p[2]*p[2], r3=p[3]*p[3],
              r4=p[4]*p[4], r5=p[5]*p[5], r6=p[6]*p[6], r7=p[7]*p[7];
        #pragma unroll 1
        for (int i = 8; i < 128; i += 8) {
            r0 += p[i+0]*p[i+0]; r1 += p[i+1]*p[i+1];
            r2 += p[i+2]*p[i+2]; r3 += p[i+3]*p[i+3];
            r4 += p[i+4]*p[i+4]; r5 += p[i+5]*p[i+5];
            r6 += p[i+6]*p[i+6]; r7 += p[i+7]*p[i+7];
        }
        float s = ((r0+r1)+(r2+r3))+((r4+r5)+(r6+r7));
        if (hb == 0) h0 = s; else h1 = s;
    }
    return h0 + h1;
}

// Zcat: per row 16 chunks (0-7 hi, 8-15 lo) x 4 quarters of 8 bf16.
// Global slot (r,c,q) holds logical quarter q ^ s(r), s(r)=(r>>1)&3  --
// so linear global_load_lds staging lands a swizzled (conflict-free) LDS image.
// Also zeroes bins[] (blocks 0..31).
__global__ void k_convert_z(const float* __restrict__ Z, unsigned short* __restrict__ Zcat,
                            float* __restrict__ bins) {
    int t = threadIdx.x;
    if (blockIdx.x < 32) bins[blockIdx.x * 256 + t] = 0.f;
    int r = blockIdx.x * 4 + (t >> 6);   // one row per wave
    int u = t & 63;                      // 64 quarters per row
    int c = u >> 2, q = u & 3;
    int lq = q ^ ((r >> 1) & 3);
    int isLo = c >> 3;
    int k0 = (c & 7) * 32 + lq * 8;
    const float4* zp = (const float4*)(Z + (size_t)r * EDIM + k0);
    float4 a = zp[0], b = zp[1];
    float f[8] = {a.x,a.y,a.z,a.w,b.x,b.y,b.z,b.w};
    uint32 o[4];
    #pragma unroll
    for (int j = 0; j < 4; ++j) {
        unsigned short w0, w1;
        unsigned short h0 = f32_to_bf16_rne(f[2*j]);
        unsigned short h1 = f32_to_bf16_rne(f[2*j+1]);
        if (isLo) {
            w0 = f32_to_bf16_rne(f[2*j]   - __uint_as_float((uint32)h0 << 16));
            w1 = f32_to_bf16_rne(f[2*j+1] - __uint_as_float((uint32)h1 << 16));
        } else { w0 = h0; w1 = h1; }
        o[j] = (uint32)w0 | ((uint32)w1 << 16);
    }
    *(uint4*)(Zcat + (size_t)r * 512 + c * 32 + q * 8) = make_uint4(o[0],o[1],o[2],o[3]);
}

// Ecat: hi-only, 8 chunks x 4 quarters, same swizzle. Also builds f32 E^T,
// computes enorm (np pairwise, one thread per row), zeroes flagcnt/lossacc.
__global__ void k_convert_e(const float* __restrict__ E, unsigned short* __restrict__ Ecat,
                            float* __restrict__ ET, float* __restrict__ en,
                            int* __restrict__ flagcnt, double* __restrict__ lossacc) {
    int t = threadIdx.x;
    if (blockIdx.x == 0 && t == 0) { *flagcnt = 0; *lossacc = 0.0; }
    int r = blockIdx.x * 8 + (t >> 5);   // row per half-wave
    int u = t & 31;
    int c = u >> 2, q = u & 3;
    int lq = q ^ ((r >> 1) & 3);
    int k0 = c * 32 + lq * 8;
    const float4* ep = (const float4*)(E + (size_t)r * EDIM + k0);
    float4 a = ep[0], b = ep[1];
    float f[8] = {a.x,a.y,a.z,a.w,b.x,b.y,b.z,b.w};
    uint32 o[4];
    #pragma unroll
    for (int j = 0; j < 4; ++j) {
        uint32 w0 = f32_to_bf16_rne(f[2*j]);
        uint32 w1 = f32_to_bf16_rne(f[2*j+1]);
        o[j] = w0 | (w1 << 16);
    }
    *(uint4*)(Ecat + (size_t)r * 256 + c * 32 + q * 8) = make_uint4(o[0],o[1],o[2],o[3]);
    #pragma unroll
    for (int j = 0; j < 8; ++j) ET[(size_t)(k0 + j) * NE + r] = f[j];
    if (u == 0) en[r] = np_pairwise_sumsq(E + (size_t)r * EDIM);
}

// merge two top-2 sets across 16-lane groups (butterfly), lex tie-break on idx
__device__ __forceinline__ void top2_shfl16(float& v1, int& i1, float& v2) {
    #pragma unroll
    for (int off = 1; off < 16; off <<= 1) {
        float ov1 = __shfl_xor(v1, off, 64);
        int   oi1 = __shfl_xor(i1, off, 64);
        float ov2 = __shfl_xor(v2, off, 64);
        bool take = (ov1 < v1) || (ov1 == v1 && oi1 < i1);
        float w1 = take ? ov1 : v1;
        int   wi = take ? oi1 : i1;
        float l1 = take ? v1  : ov1;
        v2 = fminf(fminf(v2, ov2), l1);
        v1 = w1; i1 = wi;
    }
}

// Phase A: (hi_z+lo_z).hi_e MFMA GEMM, virtual K=512. TWO 32-k chunk-sets
// staged per barrier (64 MFMA/wave per barrier): 6 x 8 KB LDS buffers.
// Score = en - 2*dot (per-row zn shift dropped: argmin/gap invariant).
__global__ __launch_bounds__(256, 3) void k_gemm(
    const unsigned short* __restrict__ Zcat, const unsigned short* __restrict__ Ecat,
    const float* __restrict__ enorm,
    float* __restrict__ pv, int* __restrict__ pi, float* __restrict__ pv2)
{
    __shared__ unsigned short Ah[2*4096];   // A hi chunk x2 sets, 16 KB
    __shared__ unsigned short Al[2*4096];   // A lo chunk x2 sets, 16 KB
    __shared__ unsigned short Bs[2*4096];   // B hi chunk x2 sets, 16 KB
    __shared__ float ens[128];
    __shared__ float cv1[2][128]; __shared__ int ci1[2][128]; __shared__ float cv2[2][128];

    int t = threadIdx.x;
    int nt = blockIdx.x & 63, mt = blockIdx.x >> 6;   // n fastest: A-band L2 reuse
    int wid = t >> 6, lane = t & 63;
    int wm = (wid >> 1) * 64, wn = (wid & 1) * 64;

    if (t < 128) ens[t] = enorm[nt*128 + t];

    // staging: wave wid fills LDS j-blocks {2w,2w+1}; lane -> row j*16+(lane>>2),
    // quarter lane&3 (matches global slot layout -> swizzled LDS image)
    int j0 = wid*2, j1 = j0 + 1;
    int r0 = j0*16 + (lane >> 2), r1 = j1*16 + (lane >> 2);
    int c8 = (lane & 3) * 8;
    const unsigned short* gA0 = Zcat + (size_t)(mt*128 + r0)*512 + c8;
    const unsigned short* gA1 = Zcat + (size_t)(mt*128 + r1)*512 + c8;
    const unsigned short* gB0 = Ecat + (size_t)(nt*128 + r0)*256 + c8;
    const unsigned short* gB1 = Ecat + (size_t)(nt*128 + r1)*256 + c8;

    f32x4 acc[4][4];
    #pragma unroll
    for (int i = 0; i < 4; ++i)
        #pragma unroll
        for (int j = 0; j < 4; ++j) acc[i][j] = (f32x4){0.f,0.f,0.f,0.f};

    // fragment read: row = frow(+16i), quarter q=lane>>4 -> LDS quarter q^s(frow)
    int frow = lane & 15, q = lane >> 4;
    int sw = (frow >> 1) & 3;
    int aFrag = (wm + frow)*32 + ((q ^ sw) * 8);
    int bFrag = (wn + frow)*32 + ((q ^ sw) * 8);

    #pragma unroll 1
    for (int cp = 0; cp < 4; ++cp) {
        int c0 = cp*2, c1 = cp*2 + 1;
        int aO0 = c0*32, aO1 = c1*32;
        // set 0
        gload_lds16(gA0 + aO0,       Ah + j0*512);
        gload_lds16(gA1 + aO0,       Ah + j1*512);
        gload_lds16(gA0 + aO0 + 256, Al + j0*512);
        gload_lds16(gA1 + aO0 + 256, Al + j1*512);
        gload_lds16(gB0 + aO0,       Bs + j0*512);
        gload_lds16(gB1 + aO0,       Bs + j1*512);
        // set 1
        gload_lds16(gA0 + aO1,       Ah + 4096 + j0*512);
        gload_lds16(gA1 + aO1,       Ah + 4096 + j1*512);
        gload_lds16(gA0 + aO1 + 256, Al + 4096 + j0*512);
        gload_lds16(gA1 + aO1 + 256, Al + 4096 + j1*512);
        gload_lds16(gB0 + aO1,       Bs + 4096 + j0*512);
        gload_lds16(gB1 + aO1,       Bs + 4096 + j1*512);
        __syncthreads();
        #pragma unroll
        for (int s = 0; s < 2; ++s) {
            int so = s * 4096;
            bf16x8 af[4], bfr[4];
            #pragma unroll
            for (int i = 0; i < 4; ++i) bfr[i] = *(const bf16x8*)(Bs + so + bFrag + i*16*32);
            #pragma unroll
            for (int i = 0; i < 4; ++i) af[i] = *(const bf16x8*)(Ah + so + aFrag + i*16*32);
            #pragma unroll
            for (int i = 0; i < 4; ++i)
                #pragma unroll
                for (int j = 0; j < 4; ++j)
                    acc[i][j] = __builtin_amdgcn_mfma_f32_16x16x32_bf16(af[i], bfr[j], acc[i][j], 0, 0, 0);
            #pragma unroll
            for (int i = 0; i < 4; ++i) af[i] = *(const bf16x8*)(Al + so + aFrag + i*16*32);
            #pragma unroll
            for (int i = 0; i < 4; ++i)
                #pragma unroll
                for (int j = 0; j < 4; ++j)
                    acc[i][j] = __builtin_amdgcn_mfma_f32_16x16x32_bf16(af[i], bfr[j], acc[i][j], 0, 0, 0);
        }
        __syncthreads();
    }

    // epilogue: D layout n = lane&15, m = (lane>>4)*4 + reg
    #pragma unroll
    for (int i = 0; i < 4; ++i) {
        #pragma unroll
        for (int r = 0; r < 4; ++r) {
            int mloc = wm + i*16 + q*4 + r;
            float s[4]; int nn[4];
            #pragma unroll
            for (int j = 0; j < 4; ++j) {
                int nl = wn + j*16 + frow;
                nn[j] = nt*128 + nl;
                s[j] = ens[nl] - 2.0f * acc[i][j][r];
            }
            float v1 = s[0], v2 = FLT_MAX; int i1 = nn[0];
            #pragma unroll
            for (int j = 1; j < 4; ++j) {
                if (s[j] < v1) { v2 = v1; v1 = s[j]; i1 = nn[j]; }
                else v2 = fminf(v2, s[j]);
            }
            top2_shfl16(v1, i1, v2);
            if (frow == 0) { cv1[wid&1][mloc] = v1; ci1[wid&1][mloc] = i1; cv2[wid&1][mloc] = v2; }
        }
    }
    __syncthreads();
    if (t < 128) {
        float v1 = cv1[0][t], v2 = cv2[0][t]; int i1 = ci1[0][t];
        float o1 = cv1[1][t], o2 = cv2[1][t]; int oi = ci1[1][t];
        if (o1 < v1 || (o1 == v1 && oi < i1)) { v2 = fminf(v1, o2); v1 = o1; i1 = oi; }
        else v2 = fminf(v2, o1);
        size_t o = (size_t)nt * N_ROWS + mt*128 + t;
        pv[o] = v1; pi[o] = i1; pv2[o] = v2;
    }
}

// merge 64 n-tile partials per row; flag rows with gap < DELTA for np-exact
// rescan (also inits packed[] for flagged rows -- replaces the memset)
__global__ void k_merge(const float* __restrict__ pv, const int* __restrict__ pi,
                        const float* __restrict__ pv2,
                        float* __restrict__ out_idx_f, int* __restrict__ idxint,
                        int* __restrict__ flagcnt, int* __restrict__ flagged,
                        uint64* __restrict__ packed) {
    int g = blockIdx.x * 256 + threadIdx.x;
    float B1 = FLT_MAX, B2 = FLT_MAX; int I1 = 0;
    #pragma unroll 1
    for (int p = 0; p < NTILES; ++p) {   // ascending p == ascending k
        size_t o = (size_t)p * N_ROWS + g;
        float v1 = pv[o], v2 = pv2[o]; int i1 = pi[o];
        if (v1 < B1) { B2 = fminf(B1, v2); B1 = v1; I1 = i1; }
        else B2 = fminf(B2, v1);
    }
    out_idx_f[g] = (float)I1;
    idxint[g] = I1;
    if (B2 - B1 < DELTA) {
        packed[g] = ~0ULL;
        int slot = atomicAdd(flagcnt, 1);
        flagged[slot] = g;
    }
}

__device__ __forceinline__ uint32 float_key(float v) {
    uint32 b = __float_as_uint(v);
    return (b & 0x80000000u) ? ~b : (b | 0x80000000u);   // monotone total order
}

// Phase B: np-exact fp32 rescan (validated round-3 semantics). Task =
// (k-slice of 1024, group of RB flagged rows); zn computed in-kernel (np order);
// result via atomicMin on order-packed (score,idx).
__global__ void k_phaseB(const float* __restrict__ Z, const float* __restrict__ ET,
                         const float* __restrict__ enorm,
                         const int* __restrict__ flagcnt, const int* __restrict__ flagged,
                         uint64* __restrict__ packed) {
    __shared__ float zl[RB][256];
    __shared__ float znl[RB];
    __shared__ int rows[RB];
    __shared__ float sv[256]; __shared__ int si[256];
    int t = threadIdx.x;
    int cnt = *flagcnt; if (cnt > N_ROWS) cnt = N_ROWS;
    int ngrp = (cnt + RB - 1) / RB;
    int ntask = ngrp * 8;
    #pragma unroll 1
    for (int task = blockIdx.x; task < ntask; task += gridDim.x) {
        int slice = task & 7;
        int g0 = (task >> 3) * RB;
        __syncthreads();
        if (t < RB) {
            int f = g0 + t;
            rows[t] = flagged[f < cnt ? f : g0];   // clamp dup: recompute harmless
        }
        __syncthreads();
        #pragma unroll
        for (int rr = 0; rr < RB; ++rr) zl[rr][t] = Z[(size_t)rows[rr]*EDIM + t];
        __syncthreads();
        if (t < RB) znl[t] = np_pairwise_sumsq(&zl[t][0]);
        __syncthreads();

        float acc[RB][4];
        #pragma unroll
        for (int rr = 0; rr < RB; ++rr)
            #pragma unroll
            for (int c = 0; c < 4; ++c) acc[rr][c] = 0.f;
        const float* eb = ET + slice*1024 + t;
        #pragma unroll 1
        for (int d = 0; d < 256; ++d) {           // sequential ascending d (np order)
            const float* ep = eb + (size_t)d * NE;
            float v0 = ep[0], v1 = ep[256], v2 = ep[512], v3 = ep[768];
            #pragma unroll
            for (int rr = 0; rr < RB; ++rr) {
                float zd = zl[rr][d];
                acc[rr][0] = fmaf(zd, v0, acc[rr][0]);
                acc[rr][1] = fmaf(zd, v1, acc[rr][1]);
                acc[rr][2] = fmaf(zd, v2, acc[rr][2]);
                acc[rr][3] = fmaf(zd, v3, acc[rr][3]);
            }
        }
        #pragma unroll 1
        for (int rr = 0; rr < RB; ++rr) {
            int row = rows[rr];
            float zn = znl[rr];
            float bv = FLT_MAX; int bi = 0x7fffffff;
            {
#pragma clang fp contract(off)
                #pragma unroll
                for (int c = 0; c < 4; ++c) {
                    int k = slice*1024 + c*256 + t;
                    float S  = zn + enorm[k];
                    float tw = 2.0f * acc[rr][c];
                    float sc = S - tw;
                    if (sc < bv || (sc == bv && k < bi)) { bv = sc; bi = k; }
                }
            }
            sv[t] = bv; si[t] = bi;
            __syncthreads();
            for (int st = 128; st > 0; st >>= 1) {
                if (t < st) {
                    float ov = sv[t+st]; int oi = si[t+st];
                    if (ov < sv[t] || (ov == sv[t] && oi < si[t])) { sv[t] = ov; si[t] = oi; }
                }
                __syncthreads();
            }
            if (t == 0) {
                uint64 pk = ((uint64)float_key(sv[0]) << 32) | (uint32)si[0];
                atomicMin(packed + row, pk);
            }
            __syncthreads();
        }
    }
}

// write back corrected idx for flagged rows
__global__ void k_fix(const int* __restrict__ flagcnt, const int* __restrict__ flagged,
                      const uint64* __restrict__ packed,
                      float* __restrict__ out_idx_f, int* __restrict__ idxint) {
    int cnt = *flagcnt; if (cnt > N_ROWS) cnt = N_ROWS;
    for (int f = blockIdx.x*256 + threadIdx.x; f < cnt; f += gridDim.x*256) {
        int row = flagged[f];
        int idx = (int)(uint32)(packed[row] & 0xffffffffu);
        out_idx_f[row] = (float)idx;
        idxint[row] = idx;
    }
}

// fused tail: z_q_st, loss, bins += 1, dw += z  (one wave per row)
__global__ void k_tail(const float* __restrict__ Z, const float* __restrict__ E,
                       const int* __restrict__ idxint,
                       float* __restrict__ out0, float* __restrict__ dw,
                       float* __restrict__ bins, double* __restrict__ lossacc) {
    __shared__ float wsum[4];
    int t = threadIdx.x;
    int w = t >> 6, lane = t & 63;
    int row = blockIdx.x * 4 + w;
    int idx = idxint[row];
    float4 z4 = ((const float4*)Z)[(size_t)row * 64 + lane];
    float4 e4 = ((const float4*)E)[(size_t)idx * 64 + lane];
    float4 d4; d4.x = e4.x - z4.x; d4.y = e4.y - z4.y; d4.z = e4.z - z4.z; d4.w = e4.w - z4.w;
    float4 o;  o.x = z4.x + d4.x;  o.y = z4.y + d4.y;  o.z = z4.z + d4.z;  o.w = z4.w + d4.w;
    ((float4*)out0)[(size_t)row * 64 + lane] = o;
    float q2 = d4.x*d4.x + d4.y*d4.y + d4.z*d4.z + d4.w*d4.w;
    #pragma unroll
    for (int off = 32; off > 0; off >>= 1) q2 += __shfl_down(q2, off, 64);
    if (lane == 0) wsum[w] = q2;
    float* dp = dw + (size_t)idx * 256 + lane * 4;
    atomicAdd(dp + 0, z4.x);
    atomicAdd(dp + 1, z4.y);
    atomicAdd(dp + 2, z4.z);
    atomicAdd(dp + 3, z4.w);
    if (lane == 0) atomicAdd(&bins[idx], 1.0f);
    __syncthreads();
    if (t == 0) atomicAdd(lossacc, (double)(wsum[0] + wsum[1] + wsum[2] + wsum[3]));
}

// new_emb = dw / cluster (in-place on out3), + loss
__global__ void k_final(const float* __restrict__ bins, const double* __restrict__ lossacc,
                        float* __restrict__ out3, float* __restrict__ out2) {
    size_t i = (size_t)blockIdx.x * 256 + threadIdx.x;
    int k = (int)(i >> 8);
    float cl = (bins[k] + 1e-5f) / (32768.0f + 8192.0f * 1e-5f) * 32768.0f;
    out3[i] = out3[i] / cl;
    if (blockIdx.x == 0 && threadIdx.x == 0)
        out2[0] = 0.25f * (float)(lossacc[0] / 8388608.0);
}

extern "C" void kernel_launch(void* const* d_in, const int* in_sizes, int n_in,
                              void* d_out, int out_size, void* d_ws, size_t ws_size,
                              hipStream_t stream) {
    const float* Z = (const float*)d_in[0];   // [32768, 256]
    const float* E = (const float*)d_in[1];   // [8192, 256]
    float* out  = (float*)d_out;
    float* out0 = out;                         // z_q_st  (8388608)
    float* out1 = out + 8388608;               // idx as float (32768)
    float* out2 = out1 + 32768;                // loss (1)
    float* out3 = out2 + 1;                    // new_embeddings (2097152)

    char* ws = (char*)d_ws;
    unsigned short* Zcat = (unsigned short*)(ws + OFF_ZCAT);
    unsigned short* Ecat = (unsigned short*)(ws + OFF_ECAT);
    float*  ET      = (float*)(ws + OFF_ET);
    float*  enorm   = (float*)(ws + OFF_EN);
    float*  pv      = (float*)(ws + OFF_PV);
    int*    pi      = (int*)  (ws + OFF_PI);
    float*  pv2     = (float*)(ws + OFF_PV2);
    int*    idxint  = (int*)  (ws + OFF_IDX);
    float*  bins    = (float*)(ws + OFF_BINS);
    uint64* packed  = (uint64*)(ws + OFF_PACKED);
    int*    flagcnt = (int*)  (ws + OFF_FLAGCNT);
    double* lossacc = (double*)(ws + OFF_LOSS);
    int*    flagged = (int*)  (ws + OFF_FLAGGED);

    hipMemsetAsync(out3, 0, (size_t)NE * EDIM * 4, stream);

    k_convert_z<<<8192, 256, 0, stream>>>(Z, Zcat, bins);
    k_convert_e<<<1024, 256, 0, stream>>>(E, Ecat, ET, enorm, flagcnt, lossacc);
    k_gemm   <<<256 * NTILES, 256, 0, stream>>>(Zcat, Ecat, enorm, pv, pi, pv2);
    k_merge  <<<N_ROWS / 256, 256, 0, stream>>>(pv, pi, pv2, out1, idxint, flagcnt, flagged, packed);
    k_phaseB <<<2048,         256, 0, stream>>>(Z, ET, enorm, flagcnt, flagged, packed);
    k_fix    <<<32,           256, 0, stream>>>(flagcnt, flagged, packed, out1, idxint);
    k_tail   <<<N_ROWS / 4,   256, 0, stream>>>(Z, E, idxint, out0, out3, bins, lossacc);
    k_final  <<<(NE*EDIM)/256,256, 0, stream>>>(bins, lossacc, out3, out2);
}